// Round 10
// baseline (8750.013 us; speedup 1.0000x reference)
//
#include <hip/hip_runtime.h>
#include <math.h>

#define Bn 128
#define Pn 625
#define ENCn 512
#define An 256
#define En 256
#define Hn 512
#define Vn 70
#define G4n 2048
#define STARTT 68
#define ENDT 69
#define NCHUNK 20
#define PCH 32
#define PSTRIDE 520
#define KSPLIT 16
#define KCH 80

// ---------------- setup kernels ----------------

__global__ __launch_bounds__(256) void k_mean(const float* __restrict__ enc,
                                              float* __restrict__ mean_enc) {
  int b = blockIdx.x, t = threadIdx.x;
  const float* e = enc + (size_t)b * Pn * ENCn;
  float s0 = 0.f, s1 = 0.f;
  for (int p = 0; p < Pn; ++p) {
    s0 += e[(size_t)p * ENCn + t];
    s1 += e[(size_t)p * ENCn + t + 256];
  }
  mean_enc[b * ENCn + t] = s0 * (1.0f / 625.0f);
  mean_enc[b * ENCn + t + 256] = s1 * (1.0f / 625.0f);
}

// one-time: Wfc -> transposed WfcT[V][H]. Exact copy; k_lstm keeps identical
// k-summation order, so preds are bit-identical to reading Wfc directly.
__global__ __launch_bounds__(256) void k_prep(const float* __restrict__ Wfc,
                                              float* __restrict__ WfcT) {
  int j = blockIdx.x * 256 + threadIdx.x;
  if (j < Hn * Vn) {
    int k = j / Vn, vv = j - k * Vn;
    WfcT[(size_t)vv * Hn + k] = Wfc[j];
  }
}

__global__ __launch_bounds__(512) void k_init(const float* __restrict__ mean_enc,
                       const float* __restrict__ Wh0, const float* __restrict__ bh0,
                       const float* __restrict__ Wc0, const float* __restrict__ bc0,
                       const float* __restrict__ emb,
                       float* __restrict__ h0, float* __restrict__ c0,
                       float* __restrict__ emb_t, int* __restrict__ done_arr) {
  int b = blockIdx.x, t = threadIdx.x;
  const float* W = blockIdx.y ? Wc0 : Wh0;
  const float* bias = blockIdx.y ? bc0 : bh0;
  float* out = blockIdx.y ? c0 : h0;
  __shared__ float ms[ENCn];
  ms[t] = mean_enc[b * ENCn + t];
  __syncthreads();
  float s = bias[t];
  for (int k = 0; k < ENCn; ++k) s += ms[k] * W[k * Hn + t];
  out[b * Hn + t] = s;
  if (blockIdx.y == 0 && t < En) emb_t[b * En + t] = emb[STARTT * En + t];
  if (blockIdx.y == 0 && b == 0 && t == 0) done_arr[0] = 0;
}

// att1 = enc @ We + be : [80000,512] @ [512,256], fp32 tiled 128x128, kt=16
__global__ __launch_bounds__(256) void k_att1(const float* __restrict__ Am,
                       const float* __restrict__ We,
                       const float* __restrict__ be, float* __restrict__ att1) {
  __shared__ float sA[16][128];
  __shared__ float sB[16][128];
  int n0 = blockIdx.x * 128, m0 = blockIdx.y * 128;
  int t = threadIdx.x;
  int tm = (t >> 4) * 8, tn = (t & 15) * 8;
  float acc[8][8];
#pragma unroll
  for (int i = 0; i < 8; ++i)
#pragma unroll
    for (int j = 0; j < 8; ++j) acc[i][j] = 0.f;
  for (int k0 = 0; k0 < 512; k0 += 16) {
    __syncthreads();
#pragma unroll
    for (int i = 0; i < 8; ++i) {
      int idx = t + i * 256;
      int mm = idx >> 4, kk = idx & 15;
      sA[kk][mm] = Am[(size_t)(m0 + mm) * 512 + k0 + kk];
      int kk2 = idx >> 7, nn = idx & 127;
      sB[kk2][nn] = We[(size_t)(k0 + kk2) * 256 + n0 + nn];
    }
    __syncthreads();
#pragma unroll
    for (int kk = 0; kk < 16; ++kk) {
      float a[8], bq[8];
      *(float4*)&a[0] = *(const float4*)&sA[kk][tm];
      *(float4*)&a[4] = *(const float4*)&sA[kk][tm + 4];
      *(float4*)&bq[0] = *(const float4*)&sB[kk][tn];
      *(float4*)&bq[4] = *(const float4*)&sB[kk][tn + 4];
#pragma unroll
      for (int i = 0; i < 8; ++i)
#pragma unroll
        for (int j = 0; j < 8; ++j) acc[i][j] += a[i] * bq[j];
    }
  }
  float ber[8];
  *(float4*)&ber[0] = *(const float4*)&be[n0 + tn];
  *(float4*)&ber[4] = *(const float4*)&be[n0 + tn + 4];
#pragma unroll
  for (int i = 0; i < 8; ++i) {
    float o[8];
#pragma unroll
    for (int j = 0; j < 8; ++j) o[j] = acc[i][j] + ber[j];
    *(float4*)&att1[(size_t)(m0 + tm + i) * An + n0 + tn] = *(float4*)&o[0];
    *(float4*)&att1[(size_t)(m0 + tm + i) * An + n0 + tn + 4] = *(float4*)&o[4];
  }
}

// ---------------- per-step kernels (R0 structure) ----------------

// blocks 0..127: att2 = h@Wd+bd, gate = sigmoid(h@Wb+bb)
// block 128: flat argmax over prev preds -> done_cur = done_prev | (idx==END)
__global__ __launch_bounds__(256) void k_proj(const float* __restrict__ h,
                       const float* __restrict__ Wd, const float* __restrict__ bd,
                       const float* __restrict__ Wb, const float* __restrict__ bbv,
                       float* __restrict__ att2, float* __restrict__ gate,
                       const float* __restrict__ preds,
                       const int* __restrict__ done_prev, int* __restrict__ done_cur,
                       int do_flat) {
  int t = threadIdx.x;
  if (blockIdx.x == Bn) {
    if (!do_flat) return;
    __shared__ float sv[256];
    __shared__ int si[256];
    float bv = -1e30f; int bi = 0x7fffffff;
    for (int i = t; i < Bn * Vn; i += 256) {
      float v = preds[i];
      if (v > bv) { bv = v; bi = i; }
    }
    sv[t] = bv; si[t] = bi;
    __syncthreads();
    for (int s = 128; s > 0; s >>= 1) {
      if (t < s) {
        if (sv[t + s] > sv[t] || (sv[t + s] == sv[t] && si[t + s] < si[t])) {
          sv[t] = sv[t + s]; si[t] = si[t + s];
        }
      }
      __syncthreads();
    }
    if (t == 0) *done_cur = (*done_prev) | (si[0] == ENDT ? 1 : 0);
    return;
  }
  int b = blockIdx.x;
  __shared__ float hsh[Hn];
  hsh[t] = h[b * Hn + t];
  hsh[t + 256] = h[b * Hn + t + 256];
  __syncthreads();
  float s0 = bd[t];
  float s1 = bbv[t], s2 = bbv[t + 256];
  for (int k = 0; k < Hn; ++k) {
    float hv = hsh[k];
    s0 += hv * Wd[(size_t)k * An + t];
    s1 += hv * Wb[(size_t)k * ENCn + t];
    s2 += hv * Wb[(size_t)k * ENCn + t + 256];
  }
  att2[b * An + t] = s0;
  gate[b * ENCn + t] = 1.f / (1.f + expf(-s1));
  gate[b * ENCn + t + 256] = 1.f / (1.f + expf(-s2));
}

// fused e -> chunk softmax -> partial weighted enc sum. grid (NCHUNK, B)
// NCHUNK=20 (PCH=32, last chunk 17): 2560 blocks = 10/CU for latency hiding.
__global__ __launch_bounds__(256) void k_attn(const float* __restrict__ att1,
                       const float* __restrict__ att2,
                       const float* __restrict__ wf, const float* __restrict__ bfp,
                       const float* __restrict__ enc, float* __restrict__ part) {
  int c = blockIdx.x, b = blockIdx.y, t = threadIdx.x;
  int lane = t & 63, wv = t >> 6;
  int p0 = c * PCH;
  int n = Pn - p0; if (n > PCH) n = PCH;
  __shared__ float es[PCH];
  __shared__ float red[256];
  float4 a2 = ((const float4*)(att2 + b * An))[lane];
  float4 wfr = ((const float4*)wf)[lane];
  float bfv = *bfp;
  const float* a1b = att1 + ((size_t)b * Pn + p0) * An;
  for (int p = wv; p < n; p += 4) {
    float4 v = ((const float4*)(a1b + (size_t)p * An))[lane];
    float s = fmaxf(v.x + a2.x, 0.f) * wfr.x
            + fmaxf(v.y + a2.y, 0.f) * wfr.y
            + fmaxf(v.z + a2.z, 0.f) * wfr.z
            + fmaxf(v.w + a2.w, 0.f) * wfr.w;
    for (int o = 32; o > 0; o >>= 1) s += __shfl_down(s, o, 64);
    if (lane == 0) es[p] = s + bfv;
  }
  __syncthreads();
  // chunk max
  float m = (t < n) ? es[t] : -1e30f;
  red[t] = m;
  __syncthreads();
  for (int s = 128; s > 0; s >>= 1) {
    if (t < s) red[t] = fmaxf(red[t], red[t + s]);
    __syncthreads();
  }
  m = red[0];
  __syncthreads();
  // exp + chunk denom
  float lp = 0.f;
  if (t < n) {
    float e2 = expf(es[t] - m);
    es[t] = e2;
    lp = e2;
  }
  red[t] = lp;
  __syncthreads();
  for (int s = 128; s > 0; s >>= 1) {
    if (t < s) red[t] += red[t + s];
    __syncthreads();
  }
  float l = red[0];
  // partial weighted sum over enc; thread t owns cols 2t, 2t+1 (row-paired)
  float acc0 = 0.f, acc1 = 0.f;
  const float* ebase = enc + ((size_t)b * Pn + p0) * ENCn;
  int p = 0;
#pragma unroll 4
  for (; p + 1 < n; p += 2) {
    float wp0 = es[p], wp1 = es[p + 1];
    float2 ev0 = ((const float2*)(ebase + (size_t)p * ENCn))[t];
    float2 ev1 = ((const float2*)(ebase + (size_t)(p + 1) * ENCn))[t];
    acc0 += wp0 * ev0.x;
    acc1 += wp0 * ev0.y;
    acc0 += wp1 * ev1.x;
    acc1 += wp1 * ev1.y;
  }
  if (p < n) {
    float wp = es[p];
    float2 ev = ((const float2*)(ebase + (size_t)p * ENCn))[t];
    acc0 += wp * ev.x;
    acc1 += wp * ev.y;
  }
  float* pp = part + (size_t)(b * NCHUNK + c) * PSTRIDE;
  if (t == 0) { pp[0] = m; pp[1] = l; }
  *(float2*)&pp[8 + 2 * t] = make_float2(acc0, acc1);
}

__global__ __launch_bounds__(256) void k_combine(const float* __restrict__ part,
                       const float* __restrict__ gate, float* __restrict__ awe) {
  int b = blockIdx.x, t = threadIdx.x;
  const float* pb = part + (size_t)b * NCHUNK * PSTRIDE;
  float M = -1e30f;
#pragma unroll
  for (int c = 0; c < NCHUNK; ++c) M = fmaxf(M, pb[c * PSTRIDE]);
  float L = 0.f, sc[NCHUNK];
#pragma unroll
  for (int c = 0; c < NCHUNK; ++c) {
    float s = expf(pb[c * PSTRIDE] - M);
    sc[c] = s;
    L += s * pb[c * PSTRIDE + 1];
  }
  float inv = 1.f / L;
  float a0 = 0.f, a1 = 0.f;
#pragma unroll
  for (int c = 0; c < NCHUNK; ++c) {
    a0 += sc[c] * pb[c * PSTRIDE + 8 + t];
    a1 += sc[c] * pb[c * PSTRIDE + 8 + t + 256];
  }
  awe[b * ENCn + t] = a0 * inv * gate[b * ENCn + t];
  awe[b * ENCn + t + 256] = a1 * inv * gate[b * ENCn + t + 256];
}

// gates partial GEMM: X=[emb_t(256); awe(512); h(512)] (K=1280) times W=[Wih;Whh] -> [128,2048]
// grid (32 col-tiles of 64, KSPLIT k-chunks of 80). thread: 8 rows x 4 cols.
__global__ __launch_bounds__(256) void k_gates(const float* __restrict__ embt,
                       const float* __restrict__ awe, const float* __restrict__ h,
                       const float* __restrict__ Wih, const float* __restrict__ Whh,
                       float* __restrict__ gp) {
  int n0 = blockIdx.x * 64;
  int sI = blockIdx.y;
  int k0 = sI * KCH;
  int t = threadIdx.x;
  int tc = t & 15, tg = t >> 4;
  int nc = n0 + tc * 4;
  float4 acc[8];
#pragma unroll
  for (int r = 0; r < 8; ++r) acc[r] = make_float4(0.f, 0.f, 0.f, 0.f);
  for (int kk = 0; kk < KCH; kk += 4) {
    int k = k0 + kk;
    const float* wbase = (k < 768) ? (Wih + (size_t)k * G4n + nc)
                                   : (Whh + (size_t)(k - 768) * G4n + nc);
    float4 w0 = *(const float4*)(wbase);
    float4 w1 = *(const float4*)(wbase + G4n);
    float4 w2 = *(const float4*)(wbase + 2 * G4n);
    float4 w3 = *(const float4*)(wbase + 3 * G4n);
#pragma unroll
    for (int r = 0; r < 8; ++r) {
      int row = tg * 8 + r;
      float4 xv;
      if (k < 256)      xv = *(const float4*)(embt + row * En + k);
      else if (k < 768) xv = *(const float4*)(awe + row * ENCn + (k - 256));
      else              xv = *(const float4*)(h + row * Hn + (k - 768));
      acc[r].x += xv.x * w0.x + xv.y * w1.x + xv.z * w2.x + xv.w * w3.x;
      acc[r].y += xv.x * w0.y + xv.y * w1.y + xv.z * w2.y + xv.w * w3.y;
      acc[r].z += xv.x * w0.z + xv.y * w1.z + xv.z * w2.z + xv.w * w3.z;
      acc[r].w += xv.x * w0.w + xv.y * w1.w + xv.z * w2.w + xv.w * w3.w;
    }
  }
#pragma unroll
  for (int r = 0; r < 8; ++r)
    *(float4*)(gp + ((size_t)sI * Bn + tg * 8 + r) * G4n + nc) = acc[r];
}

// reduce split-K partials + biases, LSTM pointwise, preds GEMV (coalesced via WfcT,
// bit-exact k-order), output write, row argmax -> next embedding. grid(B), block 512.
__global__ __launch_bounds__(512) void k_lstm(const float* __restrict__ gp,
                       const float* __restrict__ bih, const float* __restrict__ bhh,
                       const float* __restrict__ c_in, float* __restrict__ c_out,
                       float* __restrict__ h_out,
                       const float* __restrict__ WfcT, const float* __restrict__ bfc,
                       const float* __restrict__ emb, float* __restrict__ preds,
                       float* __restrict__ emb_next, float* __restrict__ out,
                       const int* __restrict__ done_t, int step, int T) {
  int b = blockIdx.x, t = threadIdx.x;
  float gi = bih[t] + bhh[t];
  float gf = bih[t + 512] + bhh[t + 512];
  float gg = bih[t + 1024] + bhh[t + 1024];
  float go = bih[t + 1536] + bhh[t + 1536];
  for (int s = 0; s < KSPLIT; ++s) {
    const float* row = gp + ((size_t)s * Bn + b) * G4n;
    gi += row[t];
    gf += row[t + 512];
    gg += row[t + 1024];
    go += row[t + 1536];
  }
  float cv = (1.f / (1.f + expf(-gf))) * c_in[b * Hn + t]
           + (1.f / (1.f + expf(-gi))) * tanhf(gg);
  float hv = (1.f / (1.f + expf(-go))) * tanhf(cv);
  c_out[b * Hn + t] = cv;
  h_out[b * Hn + t] = hv;
  __shared__ float hs[Hn];
  __shared__ float ps[Vn];
  __shared__ int tokS;
  hs[t] = hv;
  __syncthreads();
  int lane = t & 63, wvi = t >> 6;
  for (int v = wvi; v < Vn; v += 8) {
    float s = 0.f;
    for (int k = lane; k < Hn; k += 64) s += hs[k] * WfcT[(size_t)v * Hn + k];
    for (int o = 32; o > 0; o >>= 1) s += __shfl_down(s, o, 64);
    if (lane == 0) ps[v] = s + bfc[v];
  }
  __syncthreads();
  int done = *done_t;
  if (t < Vn) {
    float pv = ps[t];
    preds[b * Vn + t] = pv;
    out[((size_t)b * T + step) * Vn + t] = done ? 0.f : pv;
  }
  if (t == 0) {
    float bv = ps[0]; int bi = 0;
    for (int v = 1; v < Vn; ++v)
      if (ps[v] > bv) { bv = ps[v]; bi = v; }
    tokS = bi;
  }
  __syncthreads();
  if (t < En) emb_next[b * En + t] = emb[tokS * En + t];
}

// ---------------- host ----------------

extern "C" void kernel_launch(void* const* d_in, const int* in_sizes, int n_in,
                              void* d_out, int out_size, void* d_ws, size_t ws_size,
                              hipStream_t stream) {
  const float* enc = (const float*)d_in[0];
  const float* emb = (const float*)d_in[1];
  const float* We  = (const float*)d_in[2];
  const float* be  = (const float*)d_in[3];
  const float* Wd  = (const float*)d_in[4];
  const float* bd  = (const float*)d_in[5];
  const float* wf  = (const float*)d_in[6];
  const float* bf  = (const float*)d_in[7];
  const float* Wh0 = (const float*)d_in[8];
  const float* bh0 = (const float*)d_in[9];
  const float* Wc0 = (const float*)d_in[10];
  const float* bc0 = (const float*)d_in[11];
  const float* Wb  = (const float*)d_in[12];
  const float* bb  = (const float*)d_in[13];
  const float* Wih = (const float*)d_in[14];
  const float* Whh = (const float*)d_in[15];
  const float* bih = (const float*)d_in[16];
  const float* bhh = (const float*)d_in[17];
  const float* Wfc = (const float*)d_in[18];
  const float* bfc = (const float*)d_in[19];
  int T = out_size / (Bn * Vn);  // 70

  float* w = (float*)d_ws;
  size_t off = 0;
  float* att1 = w + off;     off += (size_t)Bn * Pn * An;       // 20.48M
  float* WfcT = w + off;     off += (size_t)Hn * Vn;
  float* mean_enc = w + off; off += Bn * ENCn;
  float* hb0 = w + off;      off += Bn * Hn;
  float* hb1 = w + off;      off += Bn * Hn;
  float* cb0 = w + off;      off += Bn * Hn;
  float* cb1 = w + off;      off += Bn * Hn;
  float* eb0 = w + off;      off += Bn * En;
  float* eb1 = w + off;      off += Bn * En;
  float* att2 = w + off;     off += Bn * An;
  float* gate = w + off;     off += Bn * ENCn;
  float* part = w + off;     off += (size_t)Bn * NCHUNK * PSTRIDE;
  float* awe = w + off;      off += Bn * ENCn;
  float* gatesP = w + off;   off += (size_t)KSPLIT * Bn * G4n;  // 4.19M
  float* preds = w + off;    off += Bn * Vn;
  off = (off + 255) & ~(size_t)255;
  int* done_arr = (int*)(w + off);

  float* hbuf[2] = {hb0, hb1};
  float* cbuf[2] = {cb0, cb1};
  float* ebuf[2] = {eb0, eb1};

  k_mean<<<Bn, 256, 0, stream>>>(enc, mean_enc);
  k_prep<<<(Hn * Vn + 255) / 256, 256, 0, stream>>>(Wfc, WfcT);
  k_init<<<dim3(Bn, 2), 512, 0, stream>>>(mean_enc, Wh0, bh0, Wc0, bc0, emb,
                                          hb0, cb0, eb0, done_arr);
  k_att1<<<dim3(2, 625), 256, 0, stream>>>(enc, We, be, att1);

  int cur = 0;
  for (int t = 0; t < T; ++t) {
    int nxt = cur ^ 1;
    k_proj<<<Bn + 1, 256, 0, stream>>>(hbuf[cur], Wd, bd, Wb, bb, att2, gate, preds,
                                       done_arr + (t > 0 ? t - 1 : 0), done_arr + t,
                                       t > 0 ? 1 : 0);
    k_attn<<<dim3(NCHUNK, Bn), 256, 0, stream>>>(att1, att2, wf, bf, enc, part);
    k_combine<<<Bn, 256, 0, stream>>>(part, gate, awe);
    k_gates<<<dim3(32, KSPLIT), 256, 0, stream>>>(ebuf[cur], awe, hbuf[cur], Wih, Whh, gatesP);
    k_lstm<<<Bn, 512, 0, stream>>>(gatesP, bih, bhh, cbuf[cur], cbuf[nxt], hbuf[nxt],
                                   WfcT, bfc, emb, preds, ebuf[nxt], (float*)d_out,
                                   done_arr + t, t, T);
    cur = nxt;
  }
}

// Round 11
// 8553.703 us; speedup vs baseline: 1.0230x; 1.0230x over previous
//
#include <hip/hip_runtime.h>
#include <math.h>

#define Bn 128
#define Pn 625
#define ENCn 512
#define An 256
#define En 256
#define Hn 512
#define Vn 70
#define G4n 2048
#define STARTT 68
#define ENDT 69
#define NCHUNK 10
#define PCH 63
#define PSTRIDE 520
#define KSPLIT 16
#define KCH 80

// ---------------- setup kernels ----------------

__global__ __launch_bounds__(256) void k_mean(const float* __restrict__ enc,
                                              float* __restrict__ mean_enc) {
  int b = blockIdx.x, t = threadIdx.x;
  const float* e = enc + (size_t)b * Pn * ENCn;
  float s0 = 0.f, s1 = 0.f;
  for (int p = 0; p < Pn; ++p) {
    s0 += e[(size_t)p * ENCn + t];
    s1 += e[(size_t)p * ENCn + t + 256];
  }
  mean_enc[b * ENCn + t] = s0 * (1.0f / 625.0f);
  mean_enc[b * ENCn + t + 256] = s1 * (1.0f / 625.0f);
}

// one-time: Wfc -> transposed WfcT[V][H]. Exact copy; k_lstm keeps identical
// k-summation order, so preds are bit-identical to reading Wfc directly.
__global__ __launch_bounds__(256) void k_prep(const float* __restrict__ Wfc,
                                              float* __restrict__ WfcT) {
  int j = blockIdx.x * 256 + threadIdx.x;
  if (j < Hn * Vn) {
    int k = j / Vn, vv = j - k * Vn;
    WfcT[(size_t)vv * Hn + k] = Wfc[j];
  }
}

__global__ __launch_bounds__(512) void k_init(const float* __restrict__ mean_enc,
                       const float* __restrict__ Wh0, const float* __restrict__ bh0,
                       const float* __restrict__ Wc0, const float* __restrict__ bc0,
                       const float* __restrict__ emb,
                       float* __restrict__ h0, float* __restrict__ c0,
                       float* __restrict__ emb_t, int* __restrict__ done_arr) {
  int b = blockIdx.x, t = threadIdx.x;
  const float* W = blockIdx.y ? Wc0 : Wh0;
  const float* bias = blockIdx.y ? bc0 : bh0;
  float* out = blockIdx.y ? c0 : h0;
  __shared__ float ms[ENCn];
  ms[t] = mean_enc[b * ENCn + t];
  __syncthreads();
  float s = bias[t];
  for (int k = 0; k < ENCn; ++k) s += ms[k] * W[k * Hn + t];
  out[b * Hn + t] = s;
  if (blockIdx.y == 0 && t < En) emb_t[b * En + t] = emb[STARTT * En + t];
  if (blockIdx.y == 0 && b == 0 && t == 0) done_arr[0] = 0;
}

// att1 = enc @ We + be : [80000,512] @ [512,256], fp32 tiled 128x128, kt=16
__global__ __launch_bounds__(256) void k_att1(const float* __restrict__ Am,
                       const float* __restrict__ We,
                       const float* __restrict__ be, float* __restrict__ att1) {
  __shared__ float sA[16][128];
  __shared__ float sB[16][128];
  int n0 = blockIdx.x * 128, m0 = blockIdx.y * 128;
  int t = threadIdx.x;
  int tm = (t >> 4) * 8, tn = (t & 15) * 8;
  float acc[8][8];
#pragma unroll
  for (int i = 0; i < 8; ++i)
#pragma unroll
    for (int j = 0; j < 8; ++j) acc[i][j] = 0.f;
  for (int k0 = 0; k0 < 512; k0 += 16) {
    __syncthreads();
#pragma unroll
    for (int i = 0; i < 8; ++i) {
      int idx = t + i * 256;
      int mm = idx >> 4, kk = idx & 15;
      sA[kk][mm] = Am[(size_t)(m0 + mm) * 512 + k0 + kk];
      int kk2 = idx >> 7, nn = idx & 127;
      sB[kk2][nn] = We[(size_t)(k0 + kk2) * 256 + n0 + nn];
    }
    __syncthreads();
#pragma unroll
    for (int kk = 0; kk < 16; ++kk) {
      float a[8], bq[8];
      *(float4*)&a[0] = *(const float4*)&sA[kk][tm];
      *(float4*)&a[4] = *(const float4*)&sA[kk][tm + 4];
      *(float4*)&bq[0] = *(const float4*)&sB[kk][tn];
      *(float4*)&bq[4] = *(const float4*)&sB[kk][tn + 4];
#pragma unroll
      for (int i = 0; i < 8; ++i)
#pragma unroll
        for (int j = 0; j < 8; ++j) acc[i][j] += a[i] * bq[j];
    }
  }
  float ber[8];
  *(float4*)&ber[0] = *(const float4*)&be[n0 + tn];
  *(float4*)&ber[4] = *(const float4*)&be[n0 + tn + 4];
#pragma unroll
  for (int i = 0; i < 8; ++i) {
    float o[8];
#pragma unroll
    for (int j = 0; j < 8; ++j) o[j] = acc[i][j] + ber[j];
    *(float4*)&att1[(size_t)(m0 + tm + i) * An + n0 + tn] = *(float4*)&o[0];
    *(float4*)&att1[(size_t)(m0 + tm + i) * An + n0 + tn + 4] = *(float4*)&o[4];
  }
}

// ---------------- per-step kernels (R0 structure) ----------------

// blocks 0..127: att2 = h@Wd+bd, gate = sigmoid(h@Wb+bb)
// block 128: flat argmax over prev preds -> done_cur = done_prev | (idx==END)
__global__ __launch_bounds__(256) void k_proj(const float* __restrict__ h,
                       const float* __restrict__ Wd, const float* __restrict__ bd,
                       const float* __restrict__ Wb, const float* __restrict__ bbv,
                       float* __restrict__ att2, float* __restrict__ gate,
                       const float* __restrict__ preds,
                       const int* __restrict__ done_prev, int* __restrict__ done_cur,
                       int do_flat) {
  int t = threadIdx.x;
  if (blockIdx.x == Bn) {
    if (!do_flat) return;
    __shared__ float sv[256];
    __shared__ int si[256];
    float bv = -1e30f; int bi = 0x7fffffff;
    for (int i = t; i < Bn * Vn; i += 256) {
      float v = preds[i];
      if (v > bv) { bv = v; bi = i; }
    }
    sv[t] = bv; si[t] = bi;
    __syncthreads();
    for (int s = 128; s > 0; s >>= 1) {
      if (t < s) {
        if (sv[t + s] > sv[t] || (sv[t + s] == sv[t] && si[t + s] < si[t])) {
          sv[t] = sv[t + s]; si[t] = si[t + s];
        }
      }
      __syncthreads();
    }
    if (t == 0) *done_cur = (*done_prev) | (si[0] == ENDT ? 1 : 0);
    return;
  }
  int b = blockIdx.x;
  __shared__ float hsh[Hn];
  hsh[t] = h[b * Hn + t];
  hsh[t + 256] = h[b * Hn + t + 256];
  __syncthreads();
  float s0 = bd[t];
  float s1 = bbv[t], s2 = bbv[t + 256];
  for (int k = 0; k < Hn; ++k) {
    float hv = hsh[k];
    s0 += hv * Wd[(size_t)k * An + t];
    s1 += hv * Wb[(size_t)k * ENCn + t];
    s2 += hv * Wb[(size_t)k * ENCn + t + 256];
  }
  att2[b * An + t] = s0;
  gate[b * ENCn + t] = 1.f / (1.f + expf(-s1));
  gate[b * ENCn + t + 256] = 1.f / (1.f + expf(-s2));
}

// fused e -> chunk softmax -> partial weighted enc sum. grid (NCHUNK, B)
// NCHUNK=10 (PCH=63, last chunk 58): 1280 blocks = 5/CU for latency hiding.
__global__ __launch_bounds__(256) void k_attn(const float* __restrict__ att1,
                       const float* __restrict__ att2,
                       const float* __restrict__ wf, const float* __restrict__ bfp,
                       const float* __restrict__ enc, float* __restrict__ part) {
  int c = blockIdx.x, b = blockIdx.y, t = threadIdx.x;
  int lane = t & 63, wv = t >> 6;
  int p0 = c * PCH;
  int n = Pn - p0; if (n > PCH) n = PCH;
  __shared__ float es[PCH];
  __shared__ float red[256];
  float4 a2 = ((const float4*)(att2 + b * An))[lane];
  float4 wfr = ((const float4*)wf)[lane];
  float bfv = *bfp;
  const float* a1b = att1 + ((size_t)b * Pn + p0) * An;
  for (int p = wv; p < n; p += 4) {
    float4 v = ((const float4*)(a1b + (size_t)p * An))[lane];
    float s = fmaxf(v.x + a2.x, 0.f) * wfr.x
            + fmaxf(v.y + a2.y, 0.f) * wfr.y
            + fmaxf(v.z + a2.z, 0.f) * wfr.z
            + fmaxf(v.w + a2.w, 0.f) * wfr.w;
    for (int o = 32; o > 0; o >>= 1) s += __shfl_down(s, o, 64);
    if (lane == 0) es[p] = s + bfv;
  }
  __syncthreads();
  // chunk max
  float m = (t < n) ? es[t] : -1e30f;
  red[t] = m;
  __syncthreads();
  for (int s = 128; s > 0; s >>= 1) {
    if (t < s) red[t] = fmaxf(red[t], red[t + s]);
    __syncthreads();
  }
  m = red[0];
  __syncthreads();
  // exp + chunk denom
  float lp = 0.f;
  if (t < n) {
    float e2 = expf(es[t] - m);
    es[t] = e2;
    lp = e2;
  }
  red[t] = lp;
  __syncthreads();
  for (int s = 128; s > 0; s >>= 1) {
    if (t < s) red[t] += red[t + s];
    __syncthreads();
  }
  float l = red[0];
  // partial weighted sum over enc; thread t owns cols 2t, 2t+1 (row-paired)
  float acc0 = 0.f, acc1 = 0.f;
  const float* ebase = enc + ((size_t)b * Pn + p0) * ENCn;
  int p = 0;
#pragma unroll 4
  for (; p + 1 < n; p += 2) {
    float wp0 = es[p], wp1 = es[p + 1];
    float2 ev0 = ((const float2*)(ebase + (size_t)p * ENCn))[t];
    float2 ev1 = ((const float2*)(ebase + (size_t)(p + 1) * ENCn))[t];
    acc0 += wp0 * ev0.x;
    acc1 += wp0 * ev0.y;
    acc0 += wp1 * ev1.x;
    acc1 += wp1 * ev1.y;
  }
  if (p < n) {
    float wp = es[p];
    float2 ev = ((const float2*)(ebase + (size_t)p * ENCn))[t];
    acc0 += wp * ev.x;
    acc1 += wp * ev.y;
  }
  float* pp = part + (size_t)(b * NCHUNK + c) * PSTRIDE;
  if (t == 0) { pp[0] = m; pp[1] = l; }
  *(float2*)&pp[8 + 2 * t] = make_float2(acc0, acc1);
}

// combine: grid (Bn, 2); block (b,y) handles cols y*256..y*256+255, one per
// thread. Per-column arithmetic order identical to the 1-block version ->
// bit-exact. 256 blocks = 1/CU (was 0.5/CU).
__global__ __launch_bounds__(256) void k_combine(const float* __restrict__ part,
                       const float* __restrict__ gate, float* __restrict__ awe) {
  int b = blockIdx.x, col = blockIdx.y * 256 + threadIdx.x;
  const float* pb = part + (size_t)b * NCHUNK * PSTRIDE;
  float M = -1e30f;
#pragma unroll
  for (int c = 0; c < NCHUNK; ++c) M = fmaxf(M, pb[c * PSTRIDE]);
  float L = 0.f, sc[NCHUNK];
#pragma unroll
  for (int c = 0; c < NCHUNK; ++c) {
    float s = expf(pb[c * PSTRIDE] - M);
    sc[c] = s;
    L += s * pb[c * PSTRIDE + 1];
  }
  float inv = 1.f / L;
  float a = 0.f;
#pragma unroll
  for (int c = 0; c < NCHUNK; ++c) a += sc[c] * pb[c * PSTRIDE + 8 + col];
  awe[b * ENCn + col] = a * inv * gate[b * ENCn + col];
}

// gates partial GEMM: X=[emb_t(256); awe(512); h(512)] (K=1280) times W=[Wih;Whh] -> [128,2048]
// grid (32 col-tiles of 64, KSPLIT k-chunks of 80). thread: 8 rows x 4 cols.
__global__ __launch_bounds__(256) void k_gates(const float* __restrict__ embt,
                       const float* __restrict__ awe, const float* __restrict__ h,
                       const float* __restrict__ Wih, const float* __restrict__ Whh,
                       float* __restrict__ gp) {
  int n0 = blockIdx.x * 64;
  int sI = blockIdx.y;
  int k0 = sI * KCH;
  int t = threadIdx.x;
  int tc = t & 15, tg = t >> 4;
  int nc = n0 + tc * 4;
  float4 acc[8];
#pragma unroll
  for (int r = 0; r < 8; ++r) acc[r] = make_float4(0.f, 0.f, 0.f, 0.f);
  for (int kk = 0; kk < KCH; kk += 4) {
    int k = k0 + kk;
    const float* wbase = (k < 768) ? (Wih + (size_t)k * G4n + nc)
                                   : (Whh + (size_t)(k - 768) * G4n + nc);
    float4 w0 = *(const float4*)(wbase);
    float4 w1 = *(const float4*)(wbase + G4n);
    float4 w2 = *(const float4*)(wbase + 2 * G4n);
    float4 w3 = *(const float4*)(wbase + 3 * G4n);
#pragma unroll
    for (int r = 0; r < 8; ++r) {
      int row = tg * 8 + r;
      float4 xv;
      if (k < 256)      xv = *(const float4*)(embt + row * En + k);
      else if (k < 768) xv = *(const float4*)(awe + row * ENCn + (k - 256));
      else              xv = *(const float4*)(h + row * Hn + (k - 768));
      acc[r].x += xv.x * w0.x + xv.y * w1.x + xv.z * w2.x + xv.w * w3.x;
      acc[r].y += xv.x * w0.y + xv.y * w1.y + xv.z * w2.y + xv.w * w3.y;
      acc[r].z += xv.x * w0.z + xv.y * w1.z + xv.z * w2.z + xv.w * w3.z;
      acc[r].w += xv.x * w0.w + xv.y * w1.w + xv.z * w2.w + xv.w * w3.w;
    }
  }
#pragma unroll
  for (int r = 0; r < 8; ++r)
    *(float4*)(gp + ((size_t)sI * Bn + tg * 8 + r) * G4n + nc) = acc[r];
}

// reduce split-K partials + biases, LSTM pointwise, preds GEMV (coalesced via WfcT,
// bit-exact k-order), output write, row argmax -> next embedding. grid(B), block 512.
__global__ __launch_bounds__(512) void k_lstm(const float* __restrict__ gp,
                       const float* __restrict__ bih, const float* __restrict__ bhh,
                       const float* __restrict__ c_in, float* __restrict__ c_out,
                       float* __restrict__ h_out,
                       const float* __restrict__ WfcT, const float* __restrict__ bfc,
                       const float* __restrict__ emb, float* __restrict__ preds,
                       float* __restrict__ emb_next, float* __restrict__ out,
                       const int* __restrict__ done_t, int step, int T) {
  int b = blockIdx.x, t = threadIdx.x;
  float gi = bih[t] + bhh[t];
  float gf = bih[t + 512] + bhh[t + 512];
  float gg = bih[t + 1024] + bhh[t + 1024];
  float go = bih[t + 1536] + bhh[t + 1536];
  for (int s = 0; s < KSPLIT; ++s) {
    const float* row = gp + ((size_t)s * Bn + b) * G4n;
    gi += row[t];
    gf += row[t + 512];
    gg += row[t + 1024];
    go += row[t + 1536];
  }
  float cv = (1.f / (1.f + expf(-gf))) * c_in[b * Hn + t]
           + (1.f / (1.f + expf(-gi))) * tanhf(gg);
  float hv = (1.f / (1.f + expf(-go))) * tanhf(cv);
  c_out[b * Hn + t] = cv;
  h_out[b * Hn + t] = hv;
  __shared__ float hs[Hn];
  __shared__ float ps[Vn];
  __shared__ int tokS;
  hs[t] = hv;
  __syncthreads();
  int lane = t & 63, wvi = t >> 6;
  for (int v = wvi; v < Vn; v += 8) {
    float s = 0.f;
    for (int k = lane; k < Hn; k += 64) s += hs[k] * WfcT[(size_t)v * Hn + k];
    for (int o = 32; o > 0; o >>= 1) s += __shfl_down(s, o, 64);
    if (lane == 0) ps[v] = s + bfc[v];
  }
  __syncthreads();
  int done = *done_t;
  if (t < Vn) {
    float pv = ps[t];
    preds[b * Vn + t] = pv;
    out[((size_t)b * T + step) * Vn + t] = done ? 0.f : pv;
  }
  if (t == 0) {
    float bv = ps[0]; int bi = 0;
    for (int v = 1; v < Vn; ++v)
      if (ps[v] > bv) { bv = ps[v]; bi = v; }
    tokS = bi;
  }
  __syncthreads();
  if (t < En) emb_next[b * En + t] = emb[tokS * En + t];
}

// ---------------- host ----------------

extern "C" void kernel_launch(void* const* d_in, const int* in_sizes, int n_in,
                              void* d_out, int out_size, void* d_ws, size_t ws_size,
                              hipStream_t stream) {
  const float* enc = (const float*)d_in[0];
  const float* emb = (const float*)d_in[1];
  const float* We  = (const float*)d_in[2];
  const float* be  = (const float*)d_in[3];
  const float* Wd  = (const float*)d_in[4];
  const float* bd  = (const float*)d_in[5];
  const float* wf  = (const float*)d_in[6];
  const float* bf  = (const float*)d_in[7];
  const float* Wh0 = (const float*)d_in[8];
  const float* bh0 = (const float*)d_in[9];
  const float* Wc0 = (const float*)d_in[10];
  const float* bc0 = (const float*)d_in[11];
  const float* Wb  = (const float*)d_in[12];
  const float* bb  = (const float*)d_in[13];
  const float* Wih = (const float*)d_in[14];
  const float* Whh = (const float*)d_in[15];
  const float* bih = (const float*)d_in[16];
  const float* bhh = (const float*)d_in[17];
  const float* Wfc = (const float*)d_in[18];
  const float* bfc = (const float*)d_in[19];
  int T = out_size / (Bn * Vn);  // 70

  float* w = (float*)d_ws;
  size_t off = 0;
  float* att1 = w + off;     off += (size_t)Bn * Pn * An;       // 20.48M
  float* WfcT = w + off;     off += (size_t)Hn * Vn;
  float* mean_enc = w + off; off += Bn * ENCn;
  float* hb0 = w + off;      off += Bn * Hn;
  float* hb1 = w + off;      off += Bn * Hn;
  float* cb0 = w + off;      off += Bn * Hn;
  float* cb1 = w + off;      off += Bn * Hn;
  float* eb0 = w + off;      off += Bn * En;
  float* eb1 = w + off;      off += Bn * En;
  float* att2 = w + off;     off += Bn * An;
  float* gate = w + off;     off += Bn * ENCn;
  float* part = w + off;     off += (size_t)Bn * NCHUNK * PSTRIDE;
  float* awe = w + off;      off += Bn * ENCn;
  float* gatesP = w + off;   off += (size_t)KSPLIT * Bn * G4n;  // 4.19M
  float* preds = w + off;    off += Bn * Vn;
  off = (off + 255) & ~(size_t)255;
  int* done_arr = (int*)(w + off);

  float* hbuf[2] = {hb0, hb1};
  float* cbuf[2] = {cb0, cb1};
  float* ebuf[2] = {eb0, eb1};

  k_mean<<<Bn, 256, 0, stream>>>(enc, mean_enc);
  k_prep<<<(Hn * Vn + 255) / 256, 256, 0, stream>>>(Wfc, WfcT);
  k_init<<<dim3(Bn, 2), 512, 0, stream>>>(mean_enc, Wh0, bh0, Wc0, bc0, emb,
                                          hb0, cb0, eb0, done_arr);
  k_att1<<<dim3(2, 625), 256, 0, stream>>>(enc, We, be, att1);

  int cur = 0;
  for (int t = 0; t < T; ++t) {
    int nxt = cur ^ 1;
    k_proj<<<Bn + 1, 256, 0, stream>>>(hbuf[cur], Wd, bd, Wb, bb, att2, gate, preds,
                                       done_arr + (t > 0 ? t - 1 : 0), done_arr + t,
                                       t > 0 ? 1 : 0);
    k_attn<<<dim3(NCHUNK, Bn), 256, 0, stream>>>(att1, att2, wf, bf, enc, part);
    k_combine<<<dim3(Bn, 2), 256, 0, stream>>>(part, gate, awe);
    k_gates<<<dim3(32, KSPLIT), 256, 0, stream>>>(ebuf[cur], awe, hbuf[cur], Wih, Whh, gatesP);
    k_lstm<<<Bn, 512, 0, stream>>>(gatesP, bih, bhh, cbuf[cur], cbuf[nxt], hbuf[nxt],
                                   WfcT, bfc, emb, preds, ebuf[nxt], (float*)d_out,
                                   done_arr + t, t, T);
    cur = nxt;
  }
}

// Round 12
// 8360.858 us; speedup vs baseline: 1.0465x; 1.0231x over previous
//
#include <hip/hip_runtime.h>
#include <math.h>

#define Bn 128
#define Pn 625
#define ENCn 512
#define An 256
#define En 256
#define Hn 512
#define Vn 70
#define G4n 2048
#define STARTT 68
#define ENDT 69
#define NCHUNK 10
#define PCH 63
#define PSTRIDE 520
#define KSPLIT 16
#define KCH 80

// ---------------- setup kernels ----------------

__global__ __launch_bounds__(256) void k_mean(const float* __restrict__ enc,
                                              float* __restrict__ mean_enc) {
  int b = blockIdx.x, t = threadIdx.x;
  const float* e = enc + (size_t)b * Pn * ENCn;
  float s0 = 0.f, s1 = 0.f;
  for (int p = 0; p < Pn; ++p) {
    s0 += e[(size_t)p * ENCn + t];
    s1 += e[(size_t)p * ENCn + t + 256];
  }
  mean_enc[b * ENCn + t] = s0 * (1.0f / 625.0f);
  mean_enc[b * ENCn + t + 256] = s1 * (1.0f / 625.0f);
}

// one-time: Wfc -> transposed WfcT[V][H]. Exact copy; k_lstm keeps identical
// k-summation order, so preds are bit-identical to reading Wfc directly.
__global__ __launch_bounds__(256) void k_prep(const float* __restrict__ Wfc,
                                              float* __restrict__ WfcT) {
  int j = blockIdx.x * 256 + threadIdx.x;
  if (j < Hn * Vn) {
    int k = j / Vn, vv = j - k * Vn;
    WfcT[(size_t)vv * Hn + k] = Wfc[j];
  }
}

__global__ __launch_bounds__(512) void k_init(const float* __restrict__ mean_enc,
                       const float* __restrict__ Wh0, const float* __restrict__ bh0,
                       const float* __restrict__ Wc0, const float* __restrict__ bc0,
                       const float* __restrict__ emb,
                       float* __restrict__ h0, float* __restrict__ c0,
                       float* __restrict__ emb_t, int* __restrict__ done_arr) {
  int b = blockIdx.x, t = threadIdx.x;
  const float* W = blockIdx.y ? Wc0 : Wh0;
  const float* bias = blockIdx.y ? bc0 : bh0;
  float* out = blockIdx.y ? c0 : h0;
  __shared__ float ms[ENCn];
  ms[t] = mean_enc[b * ENCn + t];
  __syncthreads();
  float s = bias[t];
  for (int k = 0; k < ENCn; ++k) s += ms[k] * W[k * Hn + t];
  out[b * Hn + t] = s;
  if (blockIdx.y == 0 && t < En) emb_t[b * En + t] = emb[STARTT * En + t];
  if (blockIdx.y == 0 && b == 0 && t == 0) done_arr[0] = 0;
}

// att1 = enc @ We + be : [80000,512] @ [512,256], fp32 tiled 128x128, kt=16
__global__ __launch_bounds__(256) void k_att1(const float* __restrict__ Am,
                       const float* __restrict__ We,
                       const float* __restrict__ be, float* __restrict__ att1) {
  __shared__ float sA[16][128];
  __shared__ float sB[16][128];
  int n0 = blockIdx.x * 128, m0 = blockIdx.y * 128;
  int t = threadIdx.x;
  int tm = (t >> 4) * 8, tn = (t & 15) * 8;
  float acc[8][8];
#pragma unroll
  for (int i = 0; i < 8; ++i)
#pragma unroll
    for (int j = 0; j < 8; ++j) acc[i][j] = 0.f;
  for (int k0 = 0; k0 < 512; k0 += 16) {
    __syncthreads();
#pragma unroll
    for (int i = 0; i < 8; ++i) {
      int idx = t + i * 256;
      int mm = idx >> 4, kk = idx & 15;
      sA[kk][mm] = Am[(size_t)(m0 + mm) * 512 + k0 + kk];
      int kk2 = idx >> 7, nn = idx & 127;
      sB[kk2][nn] = We[(size_t)(k0 + kk2) * 256 + n0 + nn];
    }
    __syncthreads();
#pragma unroll
    for (int kk = 0; kk < 16; ++kk) {
      float a[8], bq[8];
      *(float4*)&a[0] = *(const float4*)&sA[kk][tm];
      *(float4*)&a[4] = *(const float4*)&sA[kk][tm + 4];
      *(float4*)&bq[0] = *(const float4*)&sB[kk][tn];
      *(float4*)&bq[4] = *(const float4*)&sB[kk][tn + 4];
#pragma unroll
      for (int i = 0; i < 8; ++i)
#pragma unroll
        for (int j = 0; j < 8; ++j) acc[i][j] += a[i] * bq[j];
    }
  }
  float ber[8];
  *(float4*)&ber[0] = *(const float4*)&be[n0 + tn];
  *(float4*)&ber[4] = *(const float4*)&be[n0 + tn + 4];
#pragma unroll
  for (int i = 0; i < 8; ++i) {
    float o[8];
#pragma unroll
    for (int j = 0; j < 8; ++j) o[j] = acc[i][j] + ber[j];
    *(float4*)&att1[(size_t)(m0 + tm + i) * An + n0 + tn] = *(float4*)&o[0];
    *(float4*)&att1[(size_t)(m0 + tm + i) * An + n0 + tn + 4] = *(float4*)&o[4];
  }
}

// ---------------- per-step kernels ----------------

// grid (Bn+1, 2). block (b,0): att2[t] + gate[t] (2 chains).
//                 block (b,1): gate[t+256] (1 chain).
// block (Bn,0): flat argmax over prev preds -> done. Per-column k-order
// identical to the 1-block version -> bit-exact. 256 working blocks = 1/CU.
__global__ __launch_bounds__(256) void k_proj(const float* __restrict__ h,
                       const float* __restrict__ Wd, const float* __restrict__ bd,
                       const float* __restrict__ Wb, const float* __restrict__ bbv,
                       float* __restrict__ att2, float* __restrict__ gate,
                       const float* __restrict__ preds,
                       const int* __restrict__ done_prev, int* __restrict__ done_cur,
                       int do_flat) {
  int t = threadIdx.x;
  if (blockIdx.x == Bn) {
    if (blockIdx.y != 0 || !do_flat) return;
    __shared__ float sv[256];
    __shared__ int si[256];
    float bv = -1e30f; int bi = 0x7fffffff;
    for (int i = t; i < Bn * Vn; i += 256) {
      float v = preds[i];
      if (v > bv) { bv = v; bi = i; }
    }
    sv[t] = bv; si[t] = bi;
    __syncthreads();
    for (int s = 128; s > 0; s >>= 1) {
      if (t < s) {
        if (sv[t + s] > sv[t] || (sv[t + s] == sv[t] && si[t + s] < si[t])) {
          sv[t] = sv[t + s]; si[t] = si[t + s];
        }
      }
      __syncthreads();
    }
    if (t == 0) *done_cur = (*done_prev) | (si[0] == ENDT ? 1 : 0);
    return;
  }
  int b = blockIdx.x;
  __shared__ float hsh[Hn];
  hsh[t] = h[b * Hn + t];
  hsh[t + 256] = h[b * Hn + t + 256];
  __syncthreads();
  if (blockIdx.y == 0) {
    float s0 = bd[t];
    float s1 = bbv[t];
    for (int k = 0; k < Hn; ++k) {
      float hv = hsh[k];
      s0 += hv * Wd[(size_t)k * An + t];
      s1 += hv * Wb[(size_t)k * ENCn + t];
    }
    att2[b * An + t] = s0;
    gate[b * ENCn + t] = 1.f / (1.f + expf(-s1));
  } else {
    float s2 = bbv[t + 256];
    for (int k = 0; k < Hn; ++k) s2 += hsh[k] * Wb[(size_t)k * ENCn + t + 256];
    gate[b * ENCn + t + 256] = 1.f / (1.f + expf(-s2));
  }
}

// fused e -> chunk softmax -> partial weighted enc sum. grid (NCHUNK, B)
// NCHUNK=10 (PCH=63, last chunk 58): 1280 blocks = 5/CU for latency hiding.
__global__ __launch_bounds__(256) void k_attn(const float* __restrict__ att1,
                       const float* __restrict__ att2,
                       const float* __restrict__ wf, const float* __restrict__ bfp,
                       const float* __restrict__ enc, float* __restrict__ part) {
  int c = blockIdx.x, b = blockIdx.y, t = threadIdx.x;
  int lane = t & 63, wv = t >> 6;
  int p0 = c * PCH;
  int n = Pn - p0; if (n > PCH) n = PCH;
  __shared__ float es[PCH];
  __shared__ float red[256];
  float4 a2 = ((const float4*)(att2 + b * An))[lane];
  float4 wfr = ((const float4*)wf)[lane];
  float bfv = *bfp;
  const float* a1b = att1 + ((size_t)b * Pn + p0) * An;
  for (int p = wv; p < n; p += 4) {
    float4 v = ((const float4*)(a1b + (size_t)p * An))[lane];
    float s = fmaxf(v.x + a2.x, 0.f) * wfr.x
            + fmaxf(v.y + a2.y, 0.f) * wfr.y
            + fmaxf(v.z + a2.z, 0.f) * wfr.z
            + fmaxf(v.w + a2.w, 0.f) * wfr.w;
    for (int o = 32; o > 0; o >>= 1) s += __shfl_down(s, o, 64);
    if (lane == 0) es[p] = s + bfv;
  }
  __syncthreads();
  // chunk max
  float m = (t < n) ? es[t] : -1e30f;
  red[t] = m;
  __syncthreads();
  for (int s = 128; s > 0; s >>= 1) {
    if (t < s) red[t] = fmaxf(red[t], red[t + s]);
    __syncthreads();
  }
  m = red[0];
  __syncthreads();
  // exp + chunk denom
  float lp = 0.f;
  if (t < n) {
    float e2 = expf(es[t] - m);
    es[t] = e2;
    lp = e2;
  }
  red[t] = lp;
  __syncthreads();
  for (int s = 128; s > 0; s >>= 1) {
    if (t < s) red[t] += red[t + s];
    __syncthreads();
  }
  float l = red[0];
  // partial weighted sum over enc; thread t owns cols 2t, 2t+1 (row-paired)
  float acc0 = 0.f, acc1 = 0.f;
  const float* ebase = enc + ((size_t)b * Pn + p0) * ENCn;
  int p = 0;
#pragma unroll 4
  for (; p + 1 < n; p += 2) {
    float wp0 = es[p], wp1 = es[p + 1];
    float2 ev0 = ((const float2*)(ebase + (size_t)p * ENCn))[t];
    float2 ev1 = ((const float2*)(ebase + (size_t)(p + 1) * ENCn))[t];
    acc0 += wp0 * ev0.x;
    acc1 += wp0 * ev0.y;
    acc0 += wp1 * ev1.x;
    acc1 += wp1 * ev1.y;
  }
  if (p < n) {
    float wp = es[p];
    float2 ev = ((const float2*)(ebase + (size_t)p * ENCn))[t];
    acc0 += wp * ev.x;
    acc1 += wp * ev.y;
  }
  float* pp = part + (size_t)(b * NCHUNK + c) * PSTRIDE;
  if (t == 0) { pp[0] = m; pp[1] = l; }
  *(float2*)&pp[8 + 2 * t] = make_float2(acc0, acc1);
}

// combine: grid (Bn, 2); block (b,y) handles cols y*256..y*256+255, one per
// thread. Per-column arithmetic order identical -> bit-exact. 256 blocks = 1/CU.
__global__ __launch_bounds__(256) void k_combine(const float* __restrict__ part,
                       const float* __restrict__ gate, float* __restrict__ awe) {
  int b = blockIdx.x, col = blockIdx.y * 256 + threadIdx.x;
  const float* pb = part + (size_t)b * NCHUNK * PSTRIDE;
  float M = -1e30f;
#pragma unroll
  for (int c = 0; c < NCHUNK; ++c) M = fmaxf(M, pb[c * PSTRIDE]);
  float L = 0.f, sc[NCHUNK];
#pragma unroll
  for (int c = 0; c < NCHUNK; ++c) {
    float s = expf(pb[c * PSTRIDE] - M);
    sc[c] = s;
    L += s * pb[c * PSTRIDE + 1];
  }
  float inv = 1.f / L;
  float a = 0.f;
#pragma unroll
  for (int c = 0; c < NCHUNK; ++c) a += sc[c] * pb[c * PSTRIDE + 8 + col];
  awe[b * ENCn + col] = a * inv * gate[b * ENCn + col];
}

// gates partial GEMM: X=[emb_t(256); awe(512); h(512)] (K=1280) times W=[Wih;Whh] -> [128,2048]
// grid (32 col-tiles of 64, KSPLIT k-chunks of 80). thread: 8 rows x 4 cols.
__global__ __launch_bounds__(256) void k_gates(const float* __restrict__ embt,
                       const float* __restrict__ awe, const float* __restrict__ h,
                       const float* __restrict__ Wih, const float* __restrict__ Whh,
                       float* __restrict__ gp) {
  int n0 = blockIdx.x * 64;
  int sI = blockIdx.y;
  int k0 = sI * KCH;
  int t = threadIdx.x;
  int tc = t & 15, tg = t >> 4;
  int nc = n0 + tc * 4;
  float4 acc[8];
#pragma unroll
  for (int r = 0; r < 8; ++r) acc[r] = make_float4(0.f, 0.f, 0.f, 0.f);
  for (int kk = 0; kk < KCH; kk += 4) {
    int k = k0 + kk;
    const float* wbase = (k < 768) ? (Wih + (size_t)k * G4n + nc)
                                   : (Whh + (size_t)(k - 768) * G4n + nc);
    float4 w0 = *(const float4*)(wbase);
    float4 w1 = *(const float4*)(wbase + G4n);
    float4 w2 = *(const float4*)(wbase + 2 * G4n);
    float4 w3 = *(const float4*)(wbase + 3 * G4n);
#pragma unroll
    for (int r = 0; r < 8; ++r) {
      int row = tg * 8 + r;
      float4 xv;
      if (k < 256)      xv = *(const float4*)(embt + row * En + k);
      else if (k < 768) xv = *(const float4*)(awe + row * ENCn + (k - 256));
      else              xv = *(const float4*)(h + row * Hn + (k - 768));
      acc[r].x += xv.x * w0.x + xv.y * w1.x + xv.z * w2.x + xv.w * w3.x;
      acc[r].y += xv.x * w0.y + xv.y * w1.y + xv.z * w2.y + xv.w * w3.y;
      acc[r].z += xv.x * w0.z + xv.y * w1.z + xv.z * w2.z + xv.w * w3.z;
      acc[r].w += xv.x * w0.w + xv.y * w1.w + xv.z * w2.w + xv.w * w3.w;
    }
  }
#pragma unroll
  for (int r = 0; r < 8; ++r)
    *(float4*)(gp + ((size_t)sI * Bn + tg * 8 + r) * G4n + nc) = acc[r];
}

// reduce split-K partials + biases, LSTM pointwise, preds GEMV (coalesced via WfcT,
// bit-exact k-order), output write, row argmax -> next embedding. grid(B), block 512.
__global__ __launch_bounds__(512) void k_lstm(const float* __restrict__ gp,
                       const float* __restrict__ bih, const float* __restrict__ bhh,
                       const float* __restrict__ c_in, float* __restrict__ c_out,
                       float* __restrict__ h_out,
                       const float* __restrict__ WfcT, const float* __restrict__ bfc,
                       const float* __restrict__ emb, float* __restrict__ preds,
                       float* __restrict__ emb_next, float* __restrict__ out,
                       const int* __restrict__ done_t, int step, int T) {
  int b = blockIdx.x, t = threadIdx.x;
  float gi = bih[t] + bhh[t];
  float gf = bih[t + 512] + bhh[t + 512];
  float gg = bih[t + 1024] + bhh[t + 1024];
  float go = bih[t + 1536] + bhh[t + 1536];
  for (int s = 0; s < KSPLIT; ++s) {
    const float* row = gp + ((size_t)s * Bn + b) * G4n;
    gi += row[t];
    gf += row[t + 512];
    gg += row[t + 1024];
    go += row[t + 1536];
  }
  float cv = (1.f / (1.f + expf(-gf))) * c_in[b * Hn + t]
           + (1.f / (1.f + expf(-gi))) * tanhf(gg);
  float hv = (1.f / (1.f + expf(-go))) * tanhf(cv);
  c_out[b * Hn + t] = cv;
  h_out[b * Hn + t] = hv;
  __shared__ float hs[Hn];
  __shared__ float ps[Vn];
  __shared__ int tokS;
  hs[t] = hv;
  __syncthreads();
  int lane = t & 63, wvi = t >> 6;
  for (int v = wvi; v < Vn; v += 8) {
    float s = 0.f;
    for (int k = lane; k < Hn; k += 64) s += hs[k] * WfcT[(size_t)v * Hn + k];
    for (int o = 32; o > 0; o >>= 1) s += __shfl_down(s, o, 64);
    if (lane == 0) ps[v] = s + bfc[v];
  }
  __syncthreads();
  int done = *done_t;
  if (t < Vn) {
    float pv = ps[t];
    preds[b * Vn + t] = pv;
    out[((size_t)b * T + step) * Vn + t] = done ? 0.f : pv;
  }
  if (t == 0) {
    float bv = ps[0]; int bi = 0;
    for (int v = 1; v < Vn; ++v)
      if (ps[v] > bv) { bv = ps[v]; bi = v; }
    tokS = bi;
  }
  __syncthreads();
  if (t < En) emb_next[b * En + t] = emb[tokS * En + t];
}

// ---------------- host ----------------

extern "C" void kernel_launch(void* const* d_in, const int* in_sizes, int n_in,
                              void* d_out, int out_size, void* d_ws, size_t ws_size,
                              hipStream_t stream) {
  const float* enc = (const float*)d_in[0];
  const float* emb = (const float*)d_in[1];
  const float* We  = (const float*)d_in[2];
  const float* be  = (const float*)d_in[3];
  const float* Wd  = (const float*)d_in[4];
  const float* bd  = (const float*)d_in[5];
  const float* wf  = (const float*)d_in[6];
  const float* bf  = (const float*)d_in[7];
  const float* Wh0 = (const float*)d_in[8];
  const float* bh0 = (const float*)d_in[9];
  const float* Wc0 = (const float*)d_in[10];
  const float* bc0 = (const float*)d_in[11];
  const float* Wb  = (const float*)d_in[12];
  const float* bb  = (const float*)d_in[13];
  const float* Wih = (const float*)d_in[14];
  const float* Whh = (const float*)d_in[15];
  const float* bih = (const float*)d_in[16];
  const float* bhh = (const float*)d_in[17];
  const float* Wfc = (const float*)d_in[18];
  const float* bfc = (const float*)d_in[19];
  int T = out_size / (Bn * Vn);  // 70

  float* w = (float*)d_ws;
  size_t off = 0;
  float* att1 = w + off;     off += (size_t)Bn * Pn * An;       // 20.48M
  float* WfcT = w + off;     off += (size_t)Hn * Vn;
  float* mean_enc = w + off; off += Bn * ENCn;
  float* hb0 = w + off;      off += Bn * Hn;
  float* hb1 = w + off;      off += Bn * Hn;
  float* cb0 = w + off;      off += Bn * Hn;
  float* cb1 = w + off;      off += Bn * Hn;
  float* eb0 = w + off;      off += Bn * En;
  float* eb1 = w + off;      off += Bn * En;
  float* att2 = w + off;     off += Bn * An;
  float* gate = w + off;     off += Bn * ENCn;
  float* part = w + off;     off += (size_t)Bn * NCHUNK * PSTRIDE;
  float* awe = w + off;      off += Bn * ENCn;
  float* gatesP = w + off;   off += (size_t)KSPLIT * Bn * G4n;  // 4.19M
  float* preds = w + off;    off += Bn * Vn;
  off = (off + 255) & ~(size_t)255;
  int* done_arr = (int*)(w + off);

  float* hbuf[2] = {hb0, hb1};
  float* cbuf[2] = {cb0, cb1};
  float* ebuf[2] = {eb0, eb1};

  k_mean<<<Bn, 256, 0, stream>>>(enc, mean_enc);
  k_prep<<<(Hn * Vn + 255) / 256, 256, 0, stream>>>(Wfc, WfcT);
  k_init<<<dim3(Bn, 2), 512, 0, stream>>>(mean_enc, Wh0, bh0, Wc0, bc0, emb,
                                          hb0, cb0, eb0, done_arr);
  k_att1<<<dim3(2, 625), 256, 0, stream>>>(enc, We, be, att1);

  int cur = 0;
  for (int t = 0; t < T; ++t) {
    int nxt = cur ^ 1;
    k_proj<<<dim3(Bn + 1, 2), 256, 0, stream>>>(hbuf[cur], Wd, bd, Wb, bb, att2, gate, preds,
                                       done_arr + (t > 0 ? t - 1 : 0), done_arr + t,
                                       t > 0 ? 1 : 0);
    k_attn<<<dim3(NCHUNK, Bn), 256, 0, stream>>>(att1, att2, wf, bf, enc, part);
    k_combine<<<dim3(Bn, 2), 256, 0, stream>>>(part, gate, awe);
    k_gates<<<dim3(32, KSPLIT), 256, 0, stream>>>(ebuf[cur], awe, hbuf[cur], Wih, Whh, gatesP);
    k_lstm<<<Bn, 512, 0, stream>>>(gatesP, bih, bhh, cbuf[cur], cbuf[nxt], hbuf[nxt],
                                   WfcT, bfc, emb, preds, ebuf[nxt], (float*)d_out,
                                   done_arr + t, t, T);
    cur = nxt;
  }
}